// Round 1
// baseline (466.969 us; speedup 1.0000x reference)
//
#include <hip/hip_runtime.h>
#include <hip/hip_bf16.h>

// Problem constants
#define BQ 1024      // queries
#define NT 100000    // train latents
#define DD 256       // feature dim
#define INVT 10.0f   // 1/temperature

#define NTILE 128    // train rows per block
#define SP 264       // padded LDS row stride (bf16 elems): 528B = 132 dw, %32=4 -> <=2-way conflicts
#define NBLK 782     // ceil(100000/128)

typedef __attribute__((ext_vector_type(8))) short bf16x8;
typedef __attribute__((ext_vector_type(4))) float f32x4;

__device__ __forceinline__ unsigned short f2bf(float x) {
    union { float f; unsigned u; } a; a.f = x;
    unsigned r = (a.u + 0x7fffu + ((a.u >> 16) & 1u)) >> 16;  // RNE
    return (unsigned short)r;
}

// ---- K1: normalize q rows -> bf16. 1 wave per row. grid 256 x 256 ----
__global__ void normalize_q(const float* __restrict__ q, unsigned short* __restrict__ qn) {
    int lane = threadIdx.x & 63, wid = threadIdx.x >> 6;
    int row = blockIdx.x * 4 + wid;
    float4 v = ((const float4*)q)[row * 64 + lane];
    float s = v.x * v.x + v.y * v.y + v.z * v.z + v.w * v.w;
    #pragma unroll
    for (int m = 1; m < 64; m <<= 1) s += __shfl_xor(s, m, 64);
    float sc = rsqrtf(fmaxf(s, 1e-24f));
    unsigned lo = (unsigned)f2bf(v.x * sc) | ((unsigned)f2bf(v.y * sc) << 16);
    unsigned hi = (unsigned)f2bf(v.z * sc) | ((unsigned)f2bf(v.w * sc) << 16);
    uint2 pk; pk.x = lo; pk.y = hi;
    *(uint2*)&qn[row * DD + lane * 4] = pk;
}

// ---- K2: fused normalize-t + GEMM + softmax partials ----
__global__ __launch_bounds__(256, 1) void knn_main(const float* __restrict__ t_raw,
                                                   const unsigned short* __restrict__ qn,
                                                   float* __restrict__ acc_e,
                                                   float* __restrict__ acc_ed) {
    __shared__ unsigned short t_lds[NTILE * SP];
    __shared__ unsigned short q_lds[128 * SP];
    __shared__ float lds_e[128];
    __shared__ float lds_ed[128];

    int tid = threadIdx.x;
    int lane = tid & 63, wid = tid >> 6;
    int quad = lane >> 4, l16 = lane & 15;
    int n_base = blockIdx.x * NTILE;

    // ---- stage + fused-normalize t tile (wave per row, 8 rows in flight) ----
    for (int it = 0; it < 4; ++it) {
        int r0 = wid * 32 + it * 8;
        float4 v[8];
        #pragma unroll
        for (int j = 0; j < 8; ++j) {
            int g = n_base + r0 + j;
            if (g < NT) v[j] = ((const float4*)t_raw)[g * 64 + lane];
            else        v[j] = make_float4(0.f, 0.f, 0.f, 0.f);
        }
        #pragma unroll
        for (int j = 0; j < 8; ++j) {
            float s = v[j].x * v[j].x + v[j].y * v[j].y + v[j].z * v[j].z + v[j].w * v[j].w;
            #pragma unroll
            for (int m = 1; m < 64; m <<= 1) s += __shfl_xor(s, m, 64);
            float sc = rsqrtf(fmaxf(s, 1e-24f));
            unsigned lo = (unsigned)f2bf(v[j].x * sc) | ((unsigned)f2bf(v[j].y * sc) << 16);
            unsigned hi = (unsigned)f2bf(v[j].z * sc) | ((unsigned)f2bf(v[j].w * sc) << 16);
            uint2 pk; pk.x = lo; pk.y = hi;
            *(uint2*)&t_lds[(r0 + j) * SP + lane * 4] = pk;
        }
    }

    int wm = (wid >> 1) * 64;   // wave m-offset within chunk
    int wn = (wid & 1) * 64;    // wave n-offset within tile

    for (int mc = 0; mc < 8; ++mc) {
        __syncthreads();  // previous chunk fully consumed; t_lds ready (mc=0)
        // stage q chunk [128 x 256] bf16 from ws (L2-resident)
        #pragma unroll 4
        for (int i = 0; i < 16; ++i) {
            int r = i * 8 + (tid >> 5);
            int c = (tid & 31) * 8;
            uint4 d = *(const uint4*)&qn[(mc * 128 + r) * DD + c];
            *(uint4*)&q_lds[r * SP + c] = d;
        }
        if (tid < 128) { lds_e[tid] = 0.f; lds_ed[tid] = 0.f; }
        __syncthreads();

        // ---- MFMA: 64x64 per wave, full K=256 ----
        f32x4 acc[4][4];
        #pragma unroll
        for (int mi = 0; mi < 4; ++mi)
            #pragma unroll
            for (int ni = 0; ni < 4; ++ni)
                acc[mi][ni] = (f32x4){0.f, 0.f, 0.f, 0.f};

        #pragma unroll
        for (int k = 0; k < 8; ++k) {
            int koff = k * 32 + quad * 8;
            bf16x8 a[4], b[4];
            #pragma unroll
            for (int i = 0; i < 4; ++i)
                a[i] = *(const bf16x8*)&q_lds[(wm + i * 16 + l16) * SP + koff];
            #pragma unroll
            for (int i = 0; i < 4; ++i)
                b[i] = *(const bf16x8*)&t_lds[(wn + i * 16 + l16) * SP + koff];
            #pragma unroll
            for (int mi = 0; mi < 4; ++mi)
                #pragma unroll
                for (int ni = 0; ni < 4; ++ni)
                    acc[mi][ni] = __builtin_amdgcn_mfma_f32_16x16x32_bf16(a[mi], b[ni], acc[mi][ni], 0, 0, 0);
        }

        // ---- epilogue: dist -> exp -> per-row partials over this block's 128 cols ----
        #pragma unroll
        for (int mi = 0; mi < 4; ++mi) {
            float se[4] = {0.f, 0.f, 0.f, 0.f};
            float sd[4] = {0.f, 0.f, 0.f, 0.f};
            #pragma unroll
            for (int ni = 0; ni < 4; ++ni) {
                int ng = n_base + wn + ni * 16 + l16;
                bool valid = ng < NT;
                #pragma unroll
                for (int r = 0; r < 4; ++r) {
                    float dot = acc[mi][ni][r];
                    float d = sqrtf(fmaxf(2.0f - 2.0f * dot, 0.0f));
                    float e = valid ? __expf(-INVT * d) : 0.0f;
                    se[r] += e;
                    sd[r] += e * d;
                }
            }
            // reduce over the 16 lanes (columns) of this quad
            #pragma unroll
            for (int m = 1; m < 16; m <<= 1) {
                #pragma unroll
                for (int r = 0; r < 4; ++r) {
                    se[r] += __shfl_xor(se[r], m, 64);
                    sd[r] += __shfl_xor(sd[r], m, 64);
                }
            }
            if (l16 == 0) {
                #pragma unroll
                for (int r = 0; r < 4; ++r) {
                    int row = wm + mi * 16 + quad * 4 + r;
                    atomicAdd(&lds_e[row], se[r]);
                    atomicAdd(&lds_ed[row], sd[r]);
                }
            }
        }
        __syncthreads();
        if (tid < 128) {
            atomicAdd(&acc_e[mc * 128 + tid], lds_e[tid]);
            atomicAdd(&acc_ed[mc * 128 + tid], lds_ed[tid]);
        }
    }
}

// ---- K3: finalize ----
__global__ void finalize(const float* __restrict__ acc_e, const float* __restrict__ acc_ed,
                         float* __restrict__ out) {
    int i = blockIdx.x * 256 + threadIdx.x;
    out[i] = acc_ed[i] / acc_e[i];
}

extern "C" void kernel_launch(void* const* d_in, const int* in_sizes, int n_in,
                              void* d_out, int out_size, void* d_ws, size_t ws_size,
                              hipStream_t stream) {
    const float* q = (const float*)d_in[0];   // latent_eval [1024,256] fp32
    const float* t = (const float*)d_in[1];   // train_latents [100000,256] fp32
    float* out = (float*)d_out;               // [1024] fp32

    char* ws = (char*)d_ws;
    unsigned short* qn = (unsigned short*)ws;              // 1024*256*2 = 512 KB
    float* acc_e  = (float*)(ws + BQ * DD * 2);            // 1024 f32
    float* acc_ed = acc_e + BQ;                            // 1024 f32

    hipMemsetAsync(acc_e, 0, 2 * BQ * sizeof(float), stream);
    normalize_q<<<BQ / 4, 256, 0, stream>>>(q, qn);
    knn_main<<<NBLK, 256, 0, stream>>>(t, qn, acc_e, acc_ed);
    finalize<<<BQ / 256, 256, 0, stream>>>(acc_e, acc_ed, out);
}

// Round 2
// 226.072 us; speedup vs baseline: 2.0656x; 2.0656x over previous
//
#include <hip/hip_runtime.h>
#include <hip/hip_bf16.h>

#define NT 100000
#define NT_PAD 100032     // 1563 * 64
#define BQ 1024
#define DD 256
#define NGROUPS 128
#define NTILES 1563       // ceil(100000/64)

typedef __attribute__((ext_vector_type(8))) short bf16x8;
typedef __attribute__((ext_vector_type(4))) float f32x4;

__device__ __forceinline__ unsigned short f2bf(float x) {
    union { float f; unsigned u; } a; a.f = x;
    unsigned r = (a.u + 0x7fffu + ((a.u >> 16) & 1u)) >> 16;  // RNE
    return (unsigned short)r;
}

// async global->LDS DMA, 16B per lane; lds dest must be wave-uniform base
__device__ __forceinline__ void gl_lds16(const void* g, void* l) {
    __builtin_amdgcn_global_load_lds(
        (const __attribute__((address_space(1))) unsigned int*)g,
        (__attribute__((address_space(3))) unsigned int*)l, 16, 0, 0);
}

// ---- normalize q rows -> bf16 (1 wave per row) ----
__global__ void normalize_q(const float* __restrict__ q, unsigned short* __restrict__ qn) {
    int lane = threadIdx.x & 63, wid = threadIdx.x >> 6;
    int row = blockIdx.x * 4 + wid;
    float4 v = ((const float4*)q)[(size_t)row * 64 + lane];
    float s = v.x * v.x + v.y * v.y + v.z * v.z + v.w * v.w;
    #pragma unroll
    for (int m = 1; m < 64; m <<= 1) s += __shfl_xor(s, m, 64);
    float sc = rsqrtf(fmaxf(s, 1e-24f));
    uint2 pk;
    pk.x = (unsigned)f2bf(v.x * sc) | ((unsigned)f2bf(v.y * sc) << 16);
    pk.y = (unsigned)f2bf(v.z * sc) | ((unsigned)f2bf(v.w * sc) << 16);
    *(uint2*)&qn[(size_t)row * DD + lane * 4] = pk;
}

// ---- normalize t rows -> bf16, zero-pad to NT_PAD (1 wave per row) ----
__global__ void normalize_t(const float* __restrict__ t, unsigned short* __restrict__ tn) {
    int lane = threadIdx.x & 63, wid = threadIdx.x >> 6;
    int row = blockIdx.x * 4 + wid;   // grid covers exactly NT_PAD rows
    uint2 pk; pk.x = 0u; pk.y = 0u;
    if (row < NT) {
        float4 v = ((const float4*)t)[(size_t)row * 64 + lane];
        float s = v.x * v.x + v.y * v.y + v.z * v.z + v.w * v.w;
        #pragma unroll
        for (int m = 1; m < 64; m <<= 1) s += __shfl_xor(s, m, 64);
        float sc = rsqrtf(fmaxf(s, 1e-24f));
        pk.x = (unsigned)f2bf(v.x * sc) | ((unsigned)f2bf(v.y * sc) << 16);
        pk.y = (unsigned)f2bf(v.z * sc) | ((unsigned)f2bf(v.w * sc) << 16);
    }
    *(uint2*)&tn[(size_t)row * DD + lane * 4] = pk;
}

// Stage one 64-row t-tile into LDS with XOR-swizzled 16B chunks.
// LDS slot (row, kb) holds global chunk (row, kb ^ (row&7)); reads invert the XOR.
template<bool PRE>
__device__ __forceinline__ void stage_tile(const unsigned short* __restrict__ tn,
                                           const float* __restrict__ t_raw,
                                           unsigned short* t_lds, int ti, int w, int lane) {
    if (PRE) {
        const unsigned short* tile = tn + (size_t)ti * 64 * DD;
        int rp = lane >> 5;        // row within pair
        int kb = lane & 31;        // 16B chunk within row
        #pragma unroll
        for (int i = 0; i < 8; ++i) {
            int row = w * 16 + i * 2 + rp;
            const unsigned short* src = tile + row * DD + ((kb ^ (row & 7)) << 3);
            gl_lds16(src, &t_lds[(w * 16 + i * 2) * DD]);
        }
    } else {
        // fallback: fused normalize from fp32 (ws too small for tn)
        int n0 = ti * 64;
        for (int i = 0; i < 16; ++i) {
            int row = w * 16 + i;
            int n = n0 + row;
            float4 v = make_float4(0.f, 0.f, 0.f, 0.f);
            if (n < NT) v = ((const float4*)t_raw)[(size_t)n * 64 + lane];
            float s = v.x * v.x + v.y * v.y + v.z * v.z + v.w * v.w;
            #pragma unroll
            for (int m = 1; m < 64; m <<= 1) s += __shfl_xor(s, m, 64);
            float sc = rsqrtf(fmaxf(s, 1e-24f));
            uint2 pk;
            pk.x = (unsigned)f2bf(v.x * sc) | ((unsigned)f2bf(v.y * sc) << 16);
            pk.y = (unsigned)f2bf(v.z * sc) | ((unsigned)f2bf(v.w * sc) << 16);
            int kb16 = lane >> 1, half = lane & 1;
            *(uint2*)&t_lds[row * DD + (((kb16 ^ (row & 7)) << 3) + (half << 2))] = pk;
        }
    }
}

// ---- main: A = t-tile (n rows), B = q (m cols); D row->n, col->m ----
// Block: 128 m x 64 n per tile-iter; 4 waves, each 32 m x 64 n.
// q fragments register-resident; softmax partials reduced in-register over n
// (+2 quad shuffles), accumulated across tiles, one atomic set per wave at end.
template<bool PRE>
__global__ __launch_bounds__(256, 2) void knn_main(const unsigned short* __restrict__ tn,
                                                   const float* __restrict__ t_raw,
                                                   const unsigned short* __restrict__ qn,
                                                   float* __restrict__ acc_e,
                                                   float* __restrict__ acc_ed) {
    __shared__ unsigned short t_lds[64 * DD];   // 32 KB

    const int tid = threadIdx.x;
    const int lane = tid & 63, w = tid >> 6;
    const int quad = lane >> 4, l16 = lane & 15;
    const int swz = l16 & 7;

    const int g = blockIdx.x >> 3;       // n-group (siblings share t tiles)
    const int mchunk = blockIdx.x & 7;
    const int mbase = mchunk * 128;

    // q fragments: 2 mi x 8 ksteps, resident (64 VGPR)
    bf16x8 qf[2][8];
    {
        #pragma unroll
        for (int mi = 0; mi < 2; ++mi) {
            const unsigned short* qrow =
                qn + (size_t)(mbase + w * 32 + mi * 16 + l16) * DD + quad * 8;
            #pragma unroll
            for (int ks = 0; ks < 8; ++ks)
                qf[mi][ks] = *(const bf16x8*)(qrow + ks * 32);
        }
    }

    float se0 = 0.f, se1 = 0.f, sd0 = 0.f, sd1 = 0.f;

    stage_tile<PRE>(tn, t_raw, t_lds, g, w, lane);

    for (int ti = g; ti < NTILES; ti += NGROUPS) {
        __syncthreads();   // staged data (DMA drained) visible

        f32x4 acc[4][2];
        #pragma unroll
        for (int ni = 0; ni < 4; ++ni)
            #pragma unroll
            for (int mi = 0; mi < 2; ++mi)
                acc[ni][mi] = (f32x4){0.f, 0.f, 0.f, 0.f};

        #pragma unroll
        for (int ks = 0; ks < 8; ++ks) {
            bf16x8 a[4];
            #pragma unroll
            for (int ni = 0; ni < 4; ++ni)
                a[ni] = *(const bf16x8*)
                    &t_lds[(ni * 16 + l16) * DD + (((ks * 4 + quad) ^ swz) << 3)];
            #pragma unroll
            for (int ni = 0; ni < 4; ++ni)
                #pragma unroll
                for (int mi = 0; mi < 2; ++mi)
                    acc[ni][mi] = __builtin_amdgcn_mfma_f32_16x16x32_bf16(
                        a[ni], qf[mi][ks], acc[ni][mi], 0, 0, 0);
        }

        __syncthreads();   // all waves done reading t_lds
        int tnext = ti + NGROUPS;
        if (tnext < NTILES) stage_tile<PRE>(tn, t_raw, t_lds, tnext, w, lane);

        // epilogue (registers only — overlaps the prefetch DMA)
        const int n0 = ti * 64;
        float te0 = 0.f, te1 = 0.f, td0 = 0.f, td1 = 0.f;
        if (n0 + 64 <= NT) {
            #pragma unroll
            for (int ni = 0; ni < 4; ++ni)
                #pragma unroll
                for (int mi = 0; mi < 2; ++mi)
                    #pragma unroll
                    for (int r = 0; r < 4; ++r) {
                        float dot = acc[ni][mi][r];
                        float s = fmaf(-2.f, dot, 2.f);
                        float d = __builtin_amdgcn_sqrtf(fmaxf(s, 0.f));
                        float e = __expf(-10.f * d);
                        if (mi == 0) { te0 += e; td0 = fmaf(e, d, td0); }
                        else         { te1 += e; td1 = fmaf(e, d, td1); }
                    }
        } else {
            const int nq = n0 + quad * 4;
            #pragma unroll
            for (int ni = 0; ni < 4; ++ni)
                #pragma unroll
                for (int mi = 0; mi < 2; ++mi)
                    #pragma unroll
                    for (int r = 0; r < 4; ++r) {
                        float dot = acc[ni][mi][r];
                        float s = fmaf(-2.f, dot, 2.f);
                        float d = __builtin_amdgcn_sqrtf(fmaxf(s, 0.f));
                        float e = (nq + ni * 16 + r < NT) ? __expf(-10.f * d) : 0.f;
                        if (mi == 0) { te0 += e; td0 = fmaf(e, d, td0); }
                        else         { te1 += e; td1 = fmaf(e, d, td1); }
                    }
        }
        // reduce across quads (rows of D) — 2 shuffle steps
        #pragma unroll
        for (int m = 16; m <= 32; m <<= 1) {
            te0 += __shfl_xor(te0, m, 64);
            te1 += __shfl_xor(te1, m, 64);
            td0 += __shfl_xor(td0, m, 64);
            td1 += __shfl_xor(td1, m, 64);
        }
        se0 += te0; se1 += te1; sd0 += td0; sd1 += td1;
    }

    if (quad == 0) {
        int m0 = mbase + w * 32 + l16;
        atomicAdd(&acc_e[m0],       se0);
        atomicAdd(&acc_e[m0 + 16],  se1);
        atomicAdd(&acc_ed[m0],      sd0);
        atomicAdd(&acc_ed[m0 + 16], sd1);
    }
}

__global__ void finalize(const float* __restrict__ acc_e, const float* __restrict__ acc_ed,
                         float* __restrict__ out) {
    int i = blockIdx.x * 256 + threadIdx.x;
    out[i] = acc_ed[i] / acc_e[i];
}

extern "C" void kernel_launch(void* const* d_in, const int* in_sizes, int n_in,
                              void* d_out, int out_size, void* d_ws, size_t ws_size,
                              hipStream_t stream) {
    const float* q = (const float*)d_in[0];   // [1024,256] fp32
    const float* t = (const float*)d_in[1];   // [100000,256] fp32
    float* out = (float*)d_out;               // [1024] fp32

    char* ws = (char*)d_ws;
    float* acc_e = (float*)ws;                               // 4 KB
    float* acc_ed = acc_e + BQ;                              // 4 KB
    unsigned short* qn = (unsigned short*)(ws + 8192);       // 512 KB
    unsigned short* tn = (unsigned short*)(ws + 8192 + (size_t)BQ * DD * 2);  // 51.2 MB

    size_t needed = 8192 + (size_t)BQ * DD * 2 + (size_t)NT_PAD * DD * 2;

    hipMemsetAsync(ws, 0, 8192, stream);
    normalize_q<<<BQ / 4, 256, 0, stream>>>(q, qn);
    if (ws_size >= needed) {
        normalize_t<<<NT_PAD / 4, 256, 0, stream>>>(t, tn);
        knn_main<true><<<NGROUPS * 8, 256, 0, stream>>>(tn, t, qn, acc_e, acc_ed);
    } else {
        knn_main<false><<<NGROUPS * 8, 256, 0, stream>>>(tn, t, qn, acc_e, acc_ed);
    }
    finalize<<<BQ / 256, 256, 0, stream>>>(acc_e, acc_ed, out);
}